// Round 6
// baseline (181.150 us; speedup 1.0000x reference)
//
#include <hip/hip_runtime.h>
#include <stdint.h>
#include <stddef.h>

// y[n,o] = sum_i x[n,i]*W[n,i,o] + b[n,o]
//   W[n,i,o] = sum_j x[n,j]*Ww[j,i*128+o] + bw[i*128+o];  b = x@Wb + bb
// => Y = A@B (+bb): A[n, j*128+i] = x[n,i]*x[n,j]; B = Ww viewed [16384,128] row-major,
//    plus K-tail of 128: A[n,16384+i]=x[n,i], B[16384+i,o]=Wb[i,o]+bw[i*128+o].
// Per-j-phase factoring: aj = X_rows · B_j with raw-x fragments, acc += x[row,j]*aj.
// ROUND 6: inputs fp32 (round-5 proven: NaN vanished). OUTPUT NOW FP32 too —
// round-5 absmax 84.25 == max|y[2k+1]-y[k]| signature of the checker reading my
// packed-bf16 pairs as fp32 (ref output dtype is fp32; threshold is merely
// bf16-precision-scale). Only finish_kernel changed vs round 5.

#define NROWS   8192
#define NKT     516            // (16384+128)/32 K-tiles
#define TILE_E  4096           // 128 cols x 32 kk per K-tile image
#define XS_STRIDE 136          // 128 + 8 pad for LDS x tile
#define BM      128

typedef unsigned short u16;
typedef short short8 __attribute__((ext_vector_type(8)));
typedef unsigned short ushort8 __attribute__((ext_vector_type(8)));
typedef float floatx4 __attribute__((ext_vector_type(4)));

// Module-scope scratch (BSS; independent of d_ws).
__device__ __align__(16) u16   g_B[(size_t)NKT * TILE_E];   // 4.03 MB bf16 B image
__device__ __align__(16) u16   g_X[(size_t)NROWS * 128];    // 2 MB bf16 x image
__device__ __align__(16) float g_P[(size_t)NROWS * 128];    // 4 MB fp32 partials
__device__ int g_flag;                                      // 1 = inputs are fp32

__device__ __forceinline__ float bf2f(u16 u) {
    return __uint_as_float(((unsigned int)u) << 16);
}
__device__ __forceinline__ u16 f2bf_rne(float f) {
    unsigned int u = __float_as_uint(f);
    u += 0x7fffu + ((u >> 16) & 1u);
    return (u16)(u >> 16);
}
// dtype-polymorphic scalar load (fp32 confirmed, but keep the insurance)
__device__ __forceinline__ float ldin(const void* p, size_t idx, int isf32) {
    return isf32 ? ((const float*)p)[idx] : bf2f(((const u16*)p)[idx]);
}

// ---------------- sniff: classify input storage from Ww's raw bytes ----------------
__global__ __launch_bounds__(256) void sniff_kernel(const void* __restrict__ Ww) {
    __shared__ int s_cnt;
    if (threadIdx.x == 0) s_cnt = 0;
    __syncthreads();
    const u16* w = (const u16*)Ww;
    int c = 0;
#pragma unroll
    for (int k = 0; k < 8; ++k) {
        const u16 h = w[(threadIdx.x * 8 + k) * 2];     // even u16 = fp32 low mantissa half
        const int e = (h >> 7) & 0xFF;
        c += (e >= 96 && e <= 160) ? 1 : 0;
    }
    atomicAdd(&s_cnt, c);
    __syncthreads();
    if (threadIdx.x == 0) g_flag = (s_cnt < 1024) ? 1 : 0;   // <50% plausible -> fp32
}

// ---------------- conv: g_X = bf16(x) ----------------
__global__ __launch_bounds__(256) void conv_kernel(const void* __restrict__ x) {
    const int flat = (blockIdx.x * 256 + threadIdx.x) * 8;
    ushort8 o8;
    if (g_flag) {
        const floatx4 a = *(const floatx4*)((const float*)x + flat);
        const floatx4 b = *(const floatx4*)((const float*)x + flat + 4);
#pragma unroll
        for (int e = 0; e < 4; ++e) { o8[e] = f2bf_rne(a[e]); o8[4+e] = f2bf_rne(b[e]); }
    } else {
        o8 = *(const ushort8*)((const u16*)x + flat);
    }
    *(ushort8*)&g_X[flat] = o8;
}

// ---------------- prep: g_B[kt][o][kk] = B[kt*32+kk][o] ----------------
__global__ __launch_bounds__(256) void prep_kernel(
    const void* __restrict__ Ww, const void* __restrict__ Wb,
    const void* __restrict__ bw)
{
    const int kt   = blockIdx.x;      // 0..515
    const int t    = threadIdx.x;
    const int o    = t >> 1;          // 0..127
    const int half = t & 1;
    const int isf32 = g_flag;
    u16 buf[16];
    if (kt < 512) {
#pragma unroll
        for (int i = 0; i < 16; ++i) {
            const int kk = half*16 + i;
            buf[i] = f2bf_rne(ldin(Ww, (size_t)(kt*32 + kk)*128 + o, isf32));
        }
    } else {
#pragma unroll
        for (int i = 0; i < 16; ++i) {
            const int kk  = half*16 + i;
            const int idx = (kt - 512)*32 + kk;          // 0..127
            buf[i] = f2bf_rne(ldin(Wb, idx*128 + o, isf32) + ldin(bw, idx*128 + o, isf32));
        }
    }
    u16* outp = g_B + (size_t)kt*TILE_E + t*16;          // 32B/thread, coalesced
    ushort8 v0, v1;
#pragma unroll
    for (int e = 0; e < 8; ++e) { v0[e] = buf[e]; v1[e] = buf[8+e]; }
    ((ushort8*)outp)[0] = v0; ((ushort8*)outp)[1] = v1;
}

// ---------------- zero: g_P = 0 (g_P persists across calls) ----------------
__global__ __launch_bounds__(256) void zero_kernel() {
    const int idx = (blockIdx.x*256 + threadIdx.x) * 4;
    const floatx4 z = {0.f, 0.f, 0.f, 0.f};
    *(floatx4*)&g_P[idx] = z;
}

// ---------------- gemm: barrier-free K-loop, B direct from global image ----------------
__global__ __launch_bounds__(256, 2) void gemm_kernel()
{
    __shared__ __align__(16) u16 xs[BM * XS_STRIDE];

    const int b     = blockIdx.x;
    const int slice = b & 7;          // blockIdx%8 ~ XCD: K-slice (~530KB) L2-resident
    const int rb    = b >> 3;         // 0..63
    const int row0  = rb * BM;
    const int tid   = threadIdx.x;
    const int lane  = tid & 63;
    const int wave  = tid >> 6;
    const int wm    = wave >> 1;      // 2x2 waves, 64x64 wave tile
    const int wn    = wave & 1;
    const int l15   = lane & 15;
    const int q     = lane >> 4;

    // stage x[row0..row0+127][0..128) -> xs (padded stride), from bf16 g_X
#pragma unroll
    for (int it = 0; it < 8; ++it) {
        const int c  = it*256 + tid;
        const int r  = c >> 4;
        const int c8 = (c & 15) * 8;
        *(ushort8*)&xs[r*XS_STRIDE + c8] = *(const ushort8*)&g_X[((size_t)(row0 + r) << 7) + c8];
    }
    __syncthreads();

    // A-fragments are phase-invariant: cache all 16 in regs. A[m=l15][k=q*8+e].
    short8 af[4][4];
#pragma unroll
    for (int ks = 0; ks < 4; ++ks)
#pragma unroll
        for (int mt = 0; mt < 4; ++mt)
            af[ks][mt] = *(const short8*)&xs[(wm*64 + mt*16 + l15)*XS_STRIDE + ks*32 + q*8];

    const floatx4 fzero = {0.f, 0.f, 0.f, 0.f};
    floatx4 acc[4][4];
#pragma unroll
    for (int i = 0; i < 4; ++i)
#pragma unroll
        for (int j = 0; j < 4; ++j) acc[i][j] = fzero;

    // 129 phases (j=0..127 + bias tail 128); slice 0 takes the extra one
    const int p0 = slice*16 + (slice ? 1 : 0);
    const int np = (slice == 0) ? 17 : 16;

    for (int pp = 0; pp < np; ++pp) {
        const int p = p0 + pp;
        floatx4 aj[4][4];
#pragma unroll
        for (int i = 0; i < 4; ++i)
#pragma unroll
            for (int j = 0; j < 4; ++j) aj[i][j] = fzero;

#pragma unroll
        for (int ks = 0; ks < 4; ++ks) {
            // this wave's half-tile: cols [wn*64, wn*64+64); frag = contiguous 1KB/wave
            const u16* tb = g_B + (size_t)(p*4 + ks)*TILE_E + (wn*64)*32;
            short8 bfr[4];
#pragma unroll
            for (int nt = 0; nt < 4; ++nt)   // B[n=l15][k=q*8+e]
                bfr[nt] = *(const short8*)(tb + (nt*16 + l15)*32 + q*8);
#pragma unroll
            for (int mt = 0; mt < 4; ++mt)
#pragma unroll
                for (int nt = 0; nt < 4; ++nt)
                    aj[mt][nt] = __builtin_amdgcn_mfma_f32_16x16x32_bf16(
                        af[ks][mt], bfr[nt], aj[mt][nt], 0, 0, 0);
        }
        // acc += x[row, p] * aj   (tail phase p==128: scale 1 -> Wb+bw term)
#pragma unroll
        for (int mt = 0; mt < 4; ++mt) {
#pragma unroll
            for (int r = 0; r < 4; ++r) {
                const int rl = wm*64 + mt*16 + q*4 + r;   // C/D: row = q*4 + reg
                const float xj = (p < 128) ? bf2f(xs[rl*XS_STRIDE + p]) : 1.0f;
#pragma unroll
                for (int nt = 0; nt < 4; ++nt)
                    acc[mt][nt][r] += xj * aj[mt][nt][r];
            }
        }
    }

    // 8 K-slices reduce via device-scope atomics into zeroed g_P.
#pragma unroll
    for (int mt = 0; mt < 4; ++mt)
#pragma unroll
        for (int nt = 0; nt < 4; ++nt) {
            const int col = wn*64 + nt*16 + l15;          // C/D: col = lane&15
#pragma unroll
            for (int r = 0; r < 4; ++r) {
                const int row = row0 + wm*64 + mt*16 + q*4 + r;
                atomicAdd(&g_P[((size_t)row << 7) + col], acc[mt][nt][r]);
            }
        }
}

// ---------------- finish: + bb, write FP32 output ----------------
__global__ __launch_bounds__(256) void finish_kernel(
    const void* __restrict__ bb, float* __restrict__ out)
{
    const int flat = (blockIdx.x*256 + threadIdx.x) * 8;
    const int isf32 = g_flag;
    const floatx4 a = *(const floatx4*)&g_P[flat];
    const floatx4 c = *(const floatx4*)&g_P[flat + 4];
    floatx4 o0, o1;
#pragma unroll
    for (int e = 0; e < 4; ++e) o0[e] = a[e] + ldin(bb, (flat & 127) + e, isf32);
#pragma unroll
    for (int e = 0; e < 4; ++e) o1[e] = c[e] + ldin(bb, (flat & 127) + 4 + e, isf32);
    *(floatx4*)(out + flat)     = o0;
    *(floatx4*)(out + flat + 4) = o1;
}

extern "C" void kernel_launch(void* const* d_in, const int* in_sizes, int n_in,
                              void* d_out, int out_size, void* d_ws, size_t ws_size,
                              hipStream_t stream) {
    (void)in_sizes; (void)n_in; (void)out_size; (void)d_ws; (void)ws_size;
    const void* x  = d_in[0];
    const void* Wb = d_in[1];
    const void* bb = d_in[2];
    const void* Ww = d_in[3];
    const void* bw = d_in[4];
    float* out = (float*)d_out;

    sniff_kernel <<<dim3(1),              dim3(256), 0, stream>>>(Ww);
    conv_kernel  <<<dim3(NROWS*128/2048), dim3(256), 0, stream>>>(x);
    prep_kernel  <<<dim3(NKT),            dim3(256), 0, stream>>>(Ww, Wb, bw);
    zero_kernel  <<<dim3(NROWS*128/1024), dim3(256), 0, stream>>>();
    gemm_kernel  <<<dim3(512),            dim3(256), 0, stream>>>();
    finish_kernel<<<dim3(NROWS*128/2048), dim3(256), 0, stream>>>(bb, out);
}

// Round 7
// 147.434 us; speedup vs baseline: 1.2287x; 1.2287x over previous
//
#include <hip/hip_runtime.h>
#include <stdint.h>
#include <stddef.h>

// y[n,o] = sum_i x[n,i]*W[n,i,o] + b[n,o];  W = (x@Ww+bw) reshaped; b = x@Wb+bb.
// => Y = A@B (+bb): A[n, j*128+i] = x[n,i]*x[n,j]; B = Ww viewed [16384,128] row-major,
//    K-tail of 128: A[n,16384+i]=x[n,i], B[16384+i,o]=Wb[i,o]+bw[i*128+o].
// Per-j-phase factoring: aj = X_rows·B_j with raw-x fragments, acc += x[row,j]*aj.
// Inputs fp32, output fp32 (proven round 5/6). bf16 MFMA compute (absmax 0.25 << 1.35).
// ROUND 7: latency-bound fix — 64x32 wave tile (164 regs -> 3 waves/SIMD), grid 768
// (6 K-slices x 64 rowblocks x 2 colgroups = exactly 3 blocks/CU), double-buffered
// B-frag prefetch; 3 kernels total (prep+zero, gemm+conv, finish).

#define NROWS   8192
#define NKT     516            // (16384+128)/32 K-tiles
#define TILE_E  4096           // 128 cols x 32 kk per K-tile image (u16)
#define XS_STRIDE 136          // 128 + 8 pad for LDS x tile
#define LS_STRIDE 136
#define BM      128
#define NSLICE  6

typedef unsigned short u16;
typedef short short8 __attribute__((ext_vector_type(8)));
typedef unsigned short ushort8 __attribute__((ext_vector_type(8)));
typedef float floatx4 __attribute__((ext_vector_type(4)));

// Module-scope scratch (BSS; independent of d_ws — rounds 1-3 showed ws hazards).
__device__ __align__(16) u16   g_B[(size_t)NKT * TILE_E];   // 4.2 MB bf16 B image
__device__ __align__(16) float g_P[(size_t)NROWS * 128];    // 4 MB fp32 partials

__device__ __forceinline__ u16 f2bf_rne(float f) {
    unsigned int u = __float_as_uint(f);
    u += 0x7fffu + ((u >> 16) & 1u);
    return (u16)(u >> 16);
}

// ---------------- prep: g_B[kt][o][kk] = B[kt*32+kk][o], coalesced via LDS transpose;
//                  also zeroes g_P (kt<512 blocks). ----------------
// Tile kt<512: j=kt>>2, i0=(kt&3)*32 -> source = Ww + j*16384 + i0*128, 4096 contiguous floats
// (flat f = kk*128 + o). Tail kt>=512: Wb[idx0*128+f] + bw[idx0*128+f], both contiguous.
__global__ __launch_bounds__(256) void prep_kernel(
    const float* __restrict__ Ww, const float* __restrict__ Wb,
    const float* __restrict__ bw)
{
    __shared__ __align__(16) u16 ls[32 * LS_STRIDE];
    const int kt = blockIdx.x;
    const int t  = threadIdx.x;

    // zero g_P: 512 of the 516 blocks each clear 8KB
    if (kt < 512) {
        const int zbase = (kt*256 + t) * 8;
        const floatx4 z = {0.f, 0.f, 0.f, 0.f};
        *(floatx4*)&g_P[zbase]     = z;
        *(floatx4*)&g_P[zbase + 4] = z;
    }

    // load 16 contiguous floats -> bf16, store to ls[kk][o] (padded stride)
    float v[16];
    if (kt < 512) {
        const float* src = Ww + (size_t)(kt >> 2)*16384 + (size_t)(kt & 3)*32*128 + t*16;
#pragma unroll
        for (int c = 0; c < 4; ++c) {
            const floatx4 f4 = *(const floatx4*)(src + c*4);
#pragma unroll
            for (int e = 0; e < 4; ++e) v[c*4 + e] = f4[e];
        }
    } else {
        const size_t base = (size_t)(kt - 512)*32*128 + t*16;
        const float* s1 = Wb + base;
        const float* s2 = bw + base;
#pragma unroll
        for (int c = 0; c < 4; ++c) {
            const floatx4 a = *(const floatx4*)(s1 + c*4);
            const floatx4 b = *(const floatx4*)(s2 + c*4);
#pragma unroll
            for (int e = 0; e < 4; ++e) v[c*4 + e] = a[e] + b[e];
        }
    }
    {
        const int kk = t >> 3;            // f = t*16 -> kk = f>>7
        const int o0 = (t & 7) * 16;      // f & 127
        ushort8 w0, w1;
#pragma unroll
        for (int e = 0; e < 8; ++e) { w0[e] = f2bf_rne(v[e]); w1[e] = f2bf_rne(v[8+e]); }
        *(ushort8*)&ls[kk*LS_STRIDE + o0]     = w0;
        *(ushort8*)&ls[kk*LS_STRIDE + o0 + 8] = w1;
    }
    __syncthreads();
    // write out [o][kk]: thread t covers d = t*16..+15 -> o = t>>1, kk = (t&1)*16..+15
    {
        const int o   = t >> 1;
        const int kk0 = (t & 1) * 16;
        ushort8 w0, w1;
#pragma unroll
        for (int e = 0; e < 8; ++e) {
            w0[e] = ls[(kk0 + e)*LS_STRIDE + o];
            w1[e] = ls[(kk0 + 8 + e)*LS_STRIDE + o];
        }
        u16* outp = g_B + (size_t)kt*TILE_E + t*16;
        ((ushort8*)outp)[0] = w0; ((ushort8*)outp)[1] = w1;
    }
}

// ---------------- gemm: 64x32 wave tile, double-buffered B prefetch ----------------
// grid 768 = slice(6) x rowblock(64) x colgroup(2); block tile 128 rows x 64 cols.
__global__ __launch_bounds__(256, 3) void gemm_kernel(const float* __restrict__ x)
{
    __shared__ __align__(16) u16 xs[BM * XS_STRIDE];

    const int b     = blockIdx.x;
    const int slice = b >> 7;         // 0..5 (consecutive blocks share slice -> L2)
    const int rem   = b & 127;
    const int rb    = rem >> 1;       // 0..63
    const int cg    = rem & 1;        // col group: cols [cg*64, cg*64+64)
    const int row0  = rb * BM;
    const int tid   = threadIdx.x;
    const int lane  = tid & 63;
    const int wave  = tid >> 6;
    const int wm    = wave >> 1;      // row group: rows [wm*64, +64)
    const int wc    = wave & 1;       // col subgroup: 32 cols
    const int l15   = lane & 15;
    const int q     = lane >> 4;

    // stage x[row0..+128)[0..128) fp32 -> bf16 xs (conversion fused here)
#pragma unroll
    for (int it = 0; it < 8; ++it) {
        const int c  = it*256 + tid;
        const int r  = c >> 4;
        const int c8 = (c & 15) * 8;
        const float* sp = x + ((size_t)(row0 + r) << 7) + c8;
        const floatx4 f0 = *(const floatx4*)(sp);
        const floatx4 f1 = *(const floatx4*)(sp + 4);
        ushort8 w;
#pragma unroll
        for (int e = 0; e < 4; ++e) { w[e] = f2bf_rne(f0[e]); w[4+e] = f2bf_rne(f1[e]); }
        *(ushort8*)&xs[r*XS_STRIDE + c8] = w;
    }
    __syncthreads();

    // A-fragments cached (phase-invariant): af[ks][mt], A[m=l15][k=q*8+e]
    short8 af[4][4];
#pragma unroll
    for (int ks = 0; ks < 4; ++ks)
#pragma unroll
        for (int mt = 0; mt < 4; ++mt)
            af[ks][mt] = *(const short8*)&xs[(wm*64 + mt*16 + l15)*XS_STRIDE + ks*32 + q*8];

    const floatx4 fzero = {0.f, 0.f, 0.f, 0.f};
    floatx4 acc[4][2];
#pragma unroll
    for (int i = 0; i < 4; ++i) { acc[i][0] = fzero; acc[i][1] = fzero; }

    // phase partition: 129 phases over 6 slices (22,22,22,21,21,21)
    const int p0 = slice*21 + (slice < 3 ? slice : 3);
    const int np = 21 + (slice < 3 ? 1 : 0);

    const int colbase = cg*64 + wc*32;
    const size_t loff = (size_t)(colbase + l15)*32 + q*8;    // within-tile frag offset
    const int ktN = (p0 + np)*4;

    auto LOADB = [&](int ktl, short8* dst) {
        const u16* tb = g_B + (size_t)ktl*TILE_E + loff;
        dst[0] = *(const short8*)(tb);          // cols colbase..+15
        dst[1] = *(const short8*)(tb + 512);    // cols colbase+16..+31
    };

    short8 bufA[2], bufB[2];
    int kt = p0*4;
    LOADB(kt, bufA);

    for (int pp = 0; pp < np; ++pp) {
        const int p = p0 + pp;
        floatx4 aj[4][2];
#pragma unroll
        for (int i = 0; i < 4; ++i) { aj[i][0] = fzero; aj[i][1] = fzero; }

        // ks unrolled with two-buffer rotation; prefetch issued before MFMAs
        const int k1 = (kt+1 < ktN) ? kt+1 : ktN-1;
        LOADB(k1, bufB);
#pragma unroll
        for (int mt = 0; mt < 4; ++mt) {
            aj[mt][0] = __builtin_amdgcn_mfma_f32_16x16x32_bf16(af[0][mt], bufA[0], aj[mt][0], 0,0,0);
            aj[mt][1] = __builtin_amdgcn_mfma_f32_16x16x32_bf16(af[0][mt], bufA[1], aj[mt][1], 0,0,0);
        }
        const int k2 = (kt+2 < ktN) ? kt+2 : ktN-1;
        LOADB(k2, bufA);
#pragma unroll
        for (int mt = 0; mt < 4; ++mt) {
            aj[mt][0] = __builtin_amdgcn_mfma_f32_16x16x32_bf16(af[1][mt], bufB[0], aj[mt][0], 0,0,0);
            aj[mt][1] = __builtin_amdgcn_mfma_f32_16x16x32_bf16(af[1][mt], bufB[1], aj[mt][1], 0,0,0);
        }
        const int k3 = (kt+3 < ktN) ? kt+3 : ktN-1;
        LOADB(k3, bufB);
#pragma unroll
        for (int mt = 0; mt < 4; ++mt) {
            aj[mt][0] = __builtin_amdgcn_mfma_f32_16x16x32_bf16(af[2][mt], bufA[0], aj[mt][0], 0,0,0);
            aj[mt][1] = __builtin_amdgcn_mfma_f32_16x16x32_bf16(af[2][mt], bufA[1], aj[mt][1], 0,0,0);
        }
        const int k4 = (kt+4 < ktN) ? kt+4 : ktN-1;
        LOADB(k4, bufA);
#pragma unroll
        for (int mt = 0; mt < 4; ++mt) {
            aj[mt][0] = __builtin_amdgcn_mfma_f32_16x16x32_bf16(af[3][mt], bufB[0], aj[mt][0], 0,0,0);
            aj[mt][1] = __builtin_amdgcn_mfma_f32_16x16x32_bf16(af[3][mt], bufB[1], aj[mt][1], 0,0,0);
        }
        kt += 4;

        // acc += x_bf16[row, p] * aj   (tail phase p==128: scale 1 -> Wb+bw term)
#pragma unroll
        for (int mt = 0; mt < 4; ++mt) {
#pragma unroll
            for (int r = 0; r < 4; ++r) {
                const int rl = wm*64 + mt*16 + q*4 + r;   // C/D: row = q*4 + reg
                float xj = 1.0f;
                if (p < 128)
                    xj = __uint_as_float(((unsigned int)xs[rl*XS_STRIDE + p]) << 16);
                acc[mt][0][r] += xj * aj[mt][0][r];
                acc[mt][1][r] += xj * aj[mt][1][r];
            }
        }
    }

    // 6 K-slices reduce via device-scope atomics into zeroed g_P.
#pragma unroll
    for (int mt = 0; mt < 4; ++mt)
#pragma unroll
        for (int nt = 0; nt < 2; ++nt) {
            const int col = colbase + nt*16 + l15;        // C/D: col = lane&15
#pragma unroll
            for (int r = 0; r < 4; ++r) {
                const int row = row0 + wm*64 + mt*16 + q*4 + r;
                atomicAdd(&g_P[((size_t)row << 7) + col], acc[mt][nt][r]);
            }
        }
}

// ---------------- finish: + bb, write fp32 ----------------
__global__ __launch_bounds__(256) void finish_kernel(
    const float* __restrict__ bb, float* __restrict__ out)
{
    const int flat = (blockIdx.x*256 + threadIdx.x) * 8;
    const floatx4 a = *(const floatx4*)&g_P[flat];
    const floatx4 c = *(const floatx4*)&g_P[flat + 4];
    const floatx4 b0 = *(const floatx4*)(bb + (flat & 127));
    const floatx4 b1 = *(const floatx4*)(bb + (flat & 127) + 4);
    floatx4 o0, o1;
#pragma unroll
    for (int e = 0; e < 4; ++e) { o0[e] = a[e] + b0[e]; o1[e] = c[e] + b1[e]; }
    *(floatx4*)(out + flat)     = o0;
    *(floatx4*)(out + flat + 4) = o1;
}

extern "C" void kernel_launch(void* const* d_in, const int* in_sizes, int n_in,
                              void* d_out, int out_size, void* d_ws, size_t ws_size,
                              hipStream_t stream) {
    (void)in_sizes; (void)n_in; (void)out_size; (void)d_ws; (void)ws_size;
    const float* x  = (const float*)d_in[0];
    const float* Wb = (const float*)d_in[1];
    const float* bb = (const float*)d_in[2];
    const float* Ww = (const float*)d_in[3];
    const float* bw = (const float*)d_in[4];
    float* out = (float*)d_out;

    prep_kernel  <<<dim3(NKT),            dim3(256), 0, stream>>>(Ww, Wb, bw);
    gemm_kernel  <<<dim3(768),            dim3(256), 0, stream>>>(x);
    finish_kernel<<<dim3(NROWS*128/2048), dim3(256), 0, stream>>>(bb, out);
}